// Round 2
// baseline (160.727 us; speedup 1.0000x reference)
//
#include <hip/hip_runtime.h>
#include <stdint.h>

#define M_DIM 4096
#define K_DIM 256

typedef unsigned short us;
typedef __attribute__((ext_vector_type(8))) short bf16x8;
typedef __attribute__((ext_vector_type(4))) float f32x4;

static __device__ __forceinline__ float bf2f(unsigned int u){
  unsigned int x = u << 16; float f;
  __builtin_memcpy(&f, &x, 4); return f;
}
static __device__ __forceinline__ us f2bf(float f){
  unsigned int x; __builtin_memcpy(&x, &f, 4);
  unsigned int r = x + 0x7fffu + ((x >> 16) & 1u);
  return (us)(r >> 16);
}
static __device__ __forceinline__ void gld16(const void* g, void* l){
  __builtin_amdgcn_global_load_lds(
      (const __attribute__((address_space(1))) unsigned int*)g,
      (__attribute__((address_space(3))) unsigned int*)l, 16, 0, 0);
}

// ---- transpose+cast: [b,256,4096] f32 -> [b,4096,256] bf16, both fmaps in one launch
__global__ void k_transpose_cast(const float* __restrict__ f1,
                                 const float* __restrict__ f2,
                                 us* __restrict__ A, us* __restrict__ B0){
  __shared__ float lds[64][65];
  int z = blockIdx.z;           // 0..3 : b = z&1, which = z>>1
  int b = z & 1, which = z >> 1;
  const float* in = which ? f2 : f1;
  us* out = which ? B0 : A;
  float scale = which ? 1.0f : 0.0625f;   // fold 1/sqrt(256) into A
  int c0 = blockIdx.y * 64, m0 = blockIdx.x * 64;
  const float* ib = in + (size_t)b * K_DIM * M_DIM;
  us* ob = out + (size_t)b * M_DIM * K_DIM;
  int t = threadIdx.x, r = t >> 6, j = t & 63;
#pragma unroll
  for (int k = 0; k < 16; k++)
    lds[r + k*4][j] = ib[(size_t)(c0 + r + k*4) * M_DIM + m0 + j];
  __syncthreads();
#pragma unroll
  for (int k = 0; k < 16; k++)
    ob[(size_t)(m0 + r + k*4) * K_DIM + c0 + j] = f2bf(lds[j][r + k*4] * scale);
}

// ---- pools: B1 (2x2), B2 (4x4), B3 (8x8) all directly from B0, one launch ----------
__global__ void k_pool_all(const us* __restrict__ B0, us* __restrict__ B1,
                           us* __restrict__ B2, us* __restrict__ B3){
  int bid = blockIdx.x;
  us* dst; int wd, f;
  if (bid < 512)      { dst = B1; wd = 32; f = 2; }
  else if (bid < 640) { bid -= 512; dst = B2; wd = 16; f = 4; }
  else                { bid -= 640; dst = B3; wd = 8;  f = 8; }
  int t = threadIdx.x;
  int idx = bid * 4 + (t >> 6);
  int l = t & 63;
  int per = wd * wd;
  int b = idx / per, rem = idx - b * per;
  int y = rem / wd, x = rem - y * wd;
  const us* sb = B0 + (size_t)b * 4096 * K_DIM;
  float s0 = 0, s1 = 0, s2 = 0, s3 = 0;
  for (int dy = 0; dy < f; dy++)
    for (int dx = 0; dx < f; dx++){
      size_t off = ((size_t)(f*y + dy) * 64 + (f*x + dx)) * K_DIM + l * 4;
      uint2 v = *(const uint2*)(sb + off);
      s0 += bf2f(v.x & 0xffff); s1 += bf2f(v.x >> 16);
      s2 += bf2f(v.y & 0xffff); s3 += bf2f(v.y >> 16);
    }
  float inv = 1.0f / (float)(f * f);
  uint2 o;
  o.x = (unsigned)f2bf(s0*inv) | ((unsigned)f2bf(s1*inv) << 16);
  o.y = (unsigned)f2bf(s2*inv) | ((unsigned)f2bf(s3*inv) << 16);
  us* db = dst + (size_t)b * per * K_DIM;
  *(uint2*)(db + (size_t)rem * K_DIM + l * 4) = o;
}

// ---- all 4 GEMMs in one launch; 128x128 tile, BK=32, 2-phase LDS double-buffer -----
__global__ __launch_bounds__(256) void k_gemm_all(
    const us* __restrict__ A,
    const us* __restrict__ B0, const us* __restrict__ B1,
    const us* __restrict__ B2, const us* __restrict__ B3,
    us* __restrict__ C0, us* __restrict__ C1,
    us* __restrict__ C2, us* __restrict__ C3){
  __shared__ __align__(16) us As[2][4096];
  __shared__ __align__(16) us Bs[2][4096];
  int bx = blockIdx.x;
  const us* B; us* C; int N, n0;
  if (bx < 32)      { B = B0; C = C0; N = 4096; n0 = bx * 128; }
  else if (bx < 40) { B = B1; C = C1; N = 1024; n0 = (bx - 32) * 128; }
  else if (bx < 42) { B = B2; C = C2; N = 256;  n0 = (bx - 40) * 128; }
  else              { B = B3; C = C3; N = 64;   n0 = 0; }
  int b = blockIdx.z;
  const us* Ab = A + (size_t)b * M_DIM * K_DIM;
  const us* Bb = B + (size_t)b * N * K_DIM;
  us* Cb = C + (size_t)b * M_DIM * N;
  int m0 = blockIdx.y * 128;
  int t = threadIdx.x;
  int wave = t >> 6, lane = t & 63;
  int wm = (wave >> 1) * 64, wn = (wave & 1) * 64;
  int srow = t >> 2, scol = (t & 3) * 8;
  int fr = lane & 15, fk = (lane >> 4) * 8;
  f32x4 acc[4][4];
#pragma unroll
  for (int i = 0; i < 4; i++)
#pragma unroll
    for (int j = 0; j < 4; j++) acc[i][j] = (f32x4){0.f, 0.f, 0.f, 0.f};

  int nr0 = n0 + srow;      if (nr0 > N - 1) nr0 = N - 1;
  int nr1 = n0 + srow + 64; if (nr1 > N - 1) nr1 = N - 1;
  const us* ga0 = Ab + (size_t)(m0 + srow) * K_DIM + scol;
  const us* ga1 = Ab + (size_t)(m0 + srow + 64) * K_DIM + scol;
  const us* gb0 = Bb + (size_t)nr0 * K_DIM + scol;
  const us* gb1 = Bb + (size_t)nr1 * K_DIM + scol;

  // prologue: stage tile 0 into buffer 0
  gld16(ga0, &As[0][t*8]);
  gld16(ga1, &As[0][t*8 + 2048]);
  gld16(gb0, &Bs[0][t*8]);
  gld16(gb1, &Bs[0][t*8 + 2048]);
  asm volatile("s_waitcnt vmcnt(0)" ::: "memory");
  __syncthreads();

  int cur = 0;
  for (int it = 0; it < 8; ++it){
    if (it < 7){                       // prefetch next K-tile into other buffer
      int kt = (it + 1) * 32;
      gld16(ga0 + kt, &As[cur^1][t*8]);
      gld16(ga1 + kt, &As[cur^1][t*8 + 2048]);
      gld16(gb0 + kt, &Bs[cur^1][t*8]);
      gld16(gb1 + kt, &Bs[cur^1][t*8 + 2048]);
    }
    bf16x8 af[4], bfv[4];
#pragma unroll
    for (int i = 0; i < 4; i++)
      af[i] = *(const bf16x8*)&As[cur][(wm + i*16 + fr) * 32 + fk];
#pragma unroll
    for (int j = 0; j < 4; j++)
      bfv[j] = *(const bf16x8*)&Bs[cur][(wn + j*16 + fr) * 32 + fk];
#pragma unroll
    for (int i = 0; i < 4; i++)
#pragma unroll
      for (int j = 0; j < 4; j++)
        acc[i][j] = __builtin_amdgcn_mfma_f32_16x16x32_bf16(af[i], bfv[j], acc[i][j], 0, 0, 0);
    asm volatile("s_waitcnt vmcnt(0)" ::: "memory");
    __syncthreads();
    cur ^= 1;
  }

  int cr = (lane >> 4) * 4, ccol = lane & 15;
#pragma unroll
  for (int i = 0; i < 4; i++){
#pragma unroll
    for (int j = 0; j < 4; j++){
      int col = n0 + wn + j*16 + ccol;
      if (col < N){
        size_t base = (size_t)(m0 + wm + i*16 + cr) * N + col;
#pragma unroll
        for (int r = 0; r < 4; r++)
          Cb[base + (size_t)r * N] = f2bf(acc[i][j][r]);
      }
    }
  }
}

// ---- sampler: 8 waves per (row,batch,level); wave owns 1-2 output-d rows -----------
__global__ __launch_bounds__(512) void k_sample(
    const us* __restrict__ p0, const us* __restrict__ p1,
    const us* __restrict__ p2, const us* __restrict__ p3,
    const float* __restrict__ cc, float* __restrict__ out){
  int i = blockIdx.x, b = blockIdx.y, lvl = blockIdx.z;
  int t = threadIdx.x;
  int w = t >> 6, j = t & 63;
  const us* corr; int wl;
  if (lvl == 0)      { corr = p0; wl = 64; }
  else if (lvl == 1) { corr = p1; wl = 32; }
  else if (lvl == 2) { corr = p2; wl = 16; }
  else               { corr = p3; wl = 8;  }
  float inv = 1.0f / (float)(1 << lvl);
  int m = i * 64 + j;
  const us* rowp = corr + (size_t)(b * M_DIM + m) * (wl * wl);
  float cx = cc[((size_t)(b*2 + 0) * 64 + i) * 64 + j];
  float cy = cc[((size_t)(b*2 + 1) * 64 + i) * 64 + j];
  float x = cx * inv, y = cy * inv;
  float x0f = floorf(x), y0f = floorf(y);
  int x0 = (int)x0f, y0 = (int)y0f;
  float fx = x - x0f, fy = y - y0f;

  int d_lo  = (w == 0) ? 0 : w + 1;   // wave0: d={0,1}; wave k>=1: d={k+1}
  int d_cnt = (w == 0) ? 2 : 1;
  int nrows = d_cnt + 1;

  int bxi = x0 - 4;
  int a0 = bxi & ~1;                  // even anchor (two's-complement safe)
  int par = bxi & 1;

  float Cw[3][12];
#pragma unroll
  for (int v = 0; v < 3; v++){
    int ry = y0 - 4 + d_lo + v;
    bool vy = ((unsigned)ry < (unsigned)wl) && (v < nrows);
    int ryc = ry < 0 ? 0 : (ry > wl - 1 ? wl - 1 : ry);
    const us* rp = rowp + ryc * wl;
#pragma unroll
    for (int k = 0; k < 6; k++){
      int e = a0 + 2*k;
      int ec = e < 0 ? 0 : (e > wl - 2 ? wl - 2 : e);
      unsigned dv = *(const unsigned*)(rp + ec);
      Cw[v][2*k]   = vy ? bf2f(dv & 0xffff) : 0.0f;
      Cw[v][2*k+1] = vy ? bf2f(dv >> 16)    : 0.0f;
    }
  }
  // parity select + x-validity -> taps T[v][u] = corr[y0-4+d_lo+v][x0-4+u] or 0
  float T[3][10];
#pragma unroll
  for (int v = 0; v < 3; v++)
#pragma unroll
    for (int u = 0; u < 10; u++){
      float val = par ? Cw[v][u+1] : Cw[v][u];
      bool vx = (unsigned)(bxi + u) < (unsigned)wl;
      T[v][u] = vx ? val : 0.0f;
    }

  float wx1 = fx, wx0 = 1.0f - fx, wy1 = fy, wy0 = 1.0f - fy;
  size_t ob = (size_t)b * 324 + lvl * 81;
#pragma unroll
  for (int dd = 0; dd < 2; dd++){
    if (dd < d_cnt){
      int d = d_lo + dd;
#pragma unroll
      for (int a = 0; a < 9; a++){
        float val = wy0 * (wx0 * T[dd][a]   + wx1 * T[dd][a+1])
                  + wy1 * (wx0 * T[dd+1][a] + wx1 * T[dd+1][a+1]);
        out[((ob + a*9 + d) * 64 + i) * 64 + j] = val;
      }
    }
  }
}

extern "C" void kernel_launch(void* const* d_in, const int* in_sizes, int n_in,
                              void* d_out, int out_size, void* d_ws, size_t ws_size,
                              hipStream_t stream){
  (void)in_sizes; (void)n_in; (void)out_size; (void)ws_size;
  const float* f1 = (const float*)d_in[0];
  const float* f2 = (const float*)d_in[1];
  const float* cc = (const float*)d_in[2];
  float* out = (float*)d_out;
  char* ws = (char*)d_ws;
  us* A  = (us*)(ws + 0);          //  4 MB  f1^T bf16 (scaled 1/16)
  us* B0 = (us*)(ws + 4194304);    //  4 MB  f2^T bf16
  us* B1 = (us*)(ws + 8388608);    //  1 MB
  us* B2 = (us*)(ws + 9437184);    //  256 KB
  us* B3 = (us*)(ws + 9699328);    //  64 KB
  us* C0 = (us*)(ws + 9764864);    //  64 MB corr level 0
  us* C1 = (us*)(ws + 76873728);   //  16 MB
  us* C2 = (us*)(ws + 93650944);   //  4 MB
  us* C3 = (us*)(ws + 97845248);   //  1 MB

  k_transpose_cast<<<dim3(64, 4, 4), dim3(256), 0, stream>>>(f1, f2, A, B0);
  k_pool_all<<<dim3(672), dim3(256), 0, stream>>>(B0, B1, B2, B3);
  k_gemm_all<<<dim3(43, 32, 2), dim3(256), 0, stream>>>(A, B0, B1, B2, B3, C0, C1, C2, C3);
  k_sample<<<dim3(64, 2, 4), dim3(512), 0, stream>>>(C0, C1, C2, C3, cc, out);
}